// Round 1
// baseline (1034.027 us; speedup 1.0000x reference)
//
#include <hip/hip_runtime.h>
#include <math.h>

#define EPSF 1e-7f
constexpr int NNODE = 100;
constexpr int IN = 6;
constexpr int H = 128;
constexpr float INV_PI = 0.3183098861837907f;

__device__ __forceinline__ float clampf(float x, float lo, float hi) {
    return fminf(fmaxf(x, lo), hi);
}

// ---------------- Kernel A: per-node rotation R (row-major 3x3) + canon_vel = R^T v
__global__ void node_pre(const float* __restrict__ in, float* __restrict__ nR,
                         float* __restrict__ ncv, int total) {
    int i = blockIdx.x * blockDim.x + threadIdx.x;
    if (i >= total) return;
    const float* p = in + i * IN;
    float vx = p[3], vy = p[4], vz = p[5];
    float rho = sqrtf(vx * vx + vy * vy + vz * vz);
    float rxy = sqrtf(vx * vx + vy * vy);
    float ct, st;
    if (rxy > 1e-30f) { ct = vx / rxy; st = vy / rxy; } else { ct = 1.f; st = 0.f; }
    float cp = clampf(vz / (rho + EPSF), -1.f, 1.f);
    float sp = sqrtf(fmaxf(0.f, 1.f - cp * cp));
    float R0 = cp * ct, R1 = -st, R2 = sp * ct;
    float R3 = cp * st, R4 = ct,  R5 = sp * st;
    float R6 = -sp,     R7 = 0.f, R8 = cp;
    float* r = nR + i * 9;
    r[0] = R0; r[1] = R1; r[2] = R2;
    r[3] = R3; r[4] = R4; r[5] = R5;
    r[6] = R6; r[7] = R7; r[8] = R8;
    // canon_vel = R^T v
    float* c = ncv + i * 3;
    c[0] = R0 * vx + R3 * vy + R6 * vz;
    c[1] = R1 * vx + R4 * vy + R7 * vz;
    c[2] = R2 * vx + R5 * vy + R8 * vz;
}

// ---------------- Kernel B: reverse index recv -> list of send nodes
__global__ void build_rev(const int* __restrict__ send, const int* __restrict__ recv,
                          int* __restrict__ cnt, int* __restrict__ rev, int E) {
    int e = blockIdx.x * blockDim.x + threadIdx.x;
    if (e >= E) return;
    int r = recv[e];
    int pos = atomicAdd(&cnt[r], 1);
    rev[r * 128 + pos] = send[e];
}

// ---------------- Kernel C: fused edge features + edge MLP + mean-agg + node MLP + rotate-out
// One block per (b, n); thread c owns hidden channel c. W1/W2 columns in registers.
__global__ __launch_bounds__(128, 2)
void edge_fused(const float* __restrict__ in,
                const float* __restrict__ W1, const float* __restrict__ b1,
                const float* __restrict__ W2, const float* __restrict__ b2,
                const float* __restrict__ Wr, const float* __restrict__ br,
                const float* __restrict__ W3, const float* __restrict__ b3,
                const float* __restrict__ W4, const float* __restrict__ b4,
                const float* __restrict__ W5, const float* __restrict__ b5,
                const float* __restrict__ nR, const float* __restrict__ ncv,
                const int* __restrict__ cnt, const int* __restrict__ rev,
                float* __restrict__ out) {
    const int bn = blockIdx.x;
    const int b = bn / NNODE;
    const int n = bn - b * NNODE;
    const int c = threadIdx.x;

    __shared__ __align__(16) float ea[NNODE][12];   // per-edge unique features
    __shared__ __align__(16) float hbuf[2][H];      // double-buffered h1
    __shared__ __align__(16) float xbuf[H];         // aug / p buffers
    __shared__ float sR[9];
    __shared__ float predbuf[8];

    const float* rn = nR + bn * 9;
    float Rn[9];
#pragma unroll
    for (int k = 0; k < 9; ++k) Rn[k] = rn[k];
    if (c < 9) sR[c] = rn[c];

    const float* xi = in + bn * IN;
    float pix = xi[0], piy = xi[1], piz = xi[2];
    float cv0 = ncv[bn * 3 + 0], cv1 = ncv[bn * 3 + 1], cv2 = ncv[bn * 3 + 2];
    const int deg = cnt[n];

    // ---- phase 1: edge geometric features (thread t handles incoming edge t)
    if (c < deg) {
        int s = rev[n * 128 + c];
        const float* xj = in + (b * NNODE + s) * IN;
        float rel0 = xj[0] - pix, rel1 = xj[1] - piy, rel2 = xj[2] - piz;
        float vjx = xj[3], vjy = xj[4], vjz = xj[5];
        const float* rs = nR + (b * NNODE + s) * 9;
        float Rs0 = rs[0], Rs1 = rs[1], Rs2 = rs[2];
        float Rs3 = rs[3], Rs4 = rs[4], Rs5 = rs[5];
        float Rs6 = rs[6], Rs7 = rs[7], Rs8 = rs[8];
        // rot_rel = Rn^T rel
        float rr0 = Rn[0] * rel0 + Rn[3] * rel1 + Rn[6] * rel2;
        float rr1 = Rn[1] * rel0 + Rn[4] * rel1 + Rn[7] * rel2;
        float rr2 = Rn[2] * rel0 + Rn[5] * rel1 + Rn[8] * rel2;
        // needed entries of rot_or = Rn^T Rs
        float ro00 = Rn[0] * Rs0 + Rn[3] * Rs3 + Rn[6] * Rs6;
        float ro10 = Rn[1] * Rs0 + Rn[4] * Rs3 + Rn[7] * Rs6;
        float ro20 = Rn[2] * Rs0 + Rn[5] * Rs3 + Rn[8] * Rs6;
        float ro21 = Rn[2] * Rs1 + Rn[5] * Rs4 + Rn[8] * Rs7;
        float ro22 = Rn[2] * Rs2 + Rn[5] * Rs5 + Rn[8] * Rs8;
        float e0 = atan2f(ro10, ro00) * INV_PI;
        float e1 = asinf(clampf(-ro20, -1.f, 1.f)) * INV_PI;
        float e2 = atan2f(ro21, ro22) * INV_PI;
        float dist = sqrtf(rel0 * rel0 + rel1 * rel1 + rel2 * rel2);
        float rho_e = sqrtf(rr0 * rr0 + rr1 * rr1 + rr2 * rr2);
        float th = atan2f(rr1, rr0);
        float ph = acosf(clampf(rr2 / (rho_e + EPSF), -1.f, 1.f));
        float rv0 = Rn[0] * vjx + Rn[3] * vjy + Rn[6] * vjz;
        float rv1 = Rn[1] * vjx + Rn[4] * vjy + Rn[7] * vjz;
        float rv2 = Rn[2] * vjx + Rn[5] * vjy + Rn[8] * vjz;
        float* d = ea[c];
        d[0] = rr0; d[1] = rr1; d[2] = rr2;
        d[3] = e0;  d[4] = e1;  d[5] = e2;
        d[6] = dist; d[7] = th; d[8] = ph;
        d[9] = rv0; d[10] = rv1; d[11] = rv2;
    }

    // ---- phase 2 preload: W1/W2 columns into registers.
    // rel_feat = [0,0,0,cv] => W1 rows 12-14 dead, rows 15-17 fold into per-block bias.
    float w1c[12];
#pragma unroll
    for (int k = 0; k < 12; ++k) w1c[k] = W1[k * H + c];
    float basec = b1[c] + cv0 * W1[15 * H + c] + cv1 * W1[16 * H + c] + cv2 * W1[17 * H + c];
    float w2c[H];
#pragma unroll
    for (int k = 0; k < H; ++k) w2c[k] = W2[k * H + c];

    __syncthreads();

    // ---- edge MLP loop, agg reduced in-register
    float aggc = 0.f;
    for (int e = 0; e < deg; ++e) {
        const float4* eq = (const float4*)ea[e];
        float4 q0 = eq[0], q1 = eq[1], q2 = eq[2];
        float u0 = q0.x * w1c[0] + q0.y * w1c[1];
        float u1 = q0.z * w1c[2] + q0.w * w1c[3];
        float u2 = q1.x * w1c[4] + q1.y * w1c[5];
        float u3 = q1.z * w1c[6] + q1.w * w1c[7];
        float u4 = q2.x * w1c[8] + q2.y * w1c[9];
        float u5 = q2.z * w1c[10] + q2.w * w1c[11];
        float hp = basec + ((u0 + u1) + (u2 + u3)) + (u4 + u5);
        float h1 = hp / (1.f + __expf(-hp));   // silu
        int pbuf = e & 1;
        hbuf[pbuf][c] = h1;
        __syncthreads();
        const float4* hq = (const float4*)hbuf[pbuf];
        float a0 = 0.f, a1 = 0.f, a2 = 0.f, a3 = 0.f;
#pragma unroll
        for (int kk = 0; kk < H / 4; ++kk) {
            float4 h4 = hq[kk];
            a0 += h4.x * w2c[4 * kk + 0];
            a1 += h4.y * w2c[4 * kk + 1];
            a2 += h4.z * w2c[4 * kk + 2];
            a3 += h4.w * w2c[4 * kk + 3];
        }
        aggc += (a0 + a1) + (a2 + a3);
    }

    // ---- node MLP epilogue (fused, all in this block)
    int degc = deg < 1 ? 1 : deg;
    float invdeg = 1.f / (float)degc;
    float aug = (aggc + (float)deg * b2[c]) * invdeg
              + cv0 * Wr[3 * H + c] + cv1 * Wr[4 * H + c] + cv2 * Wr[5 * H + c] + br[c];
    __syncthreads();
    xbuf[c] = aug;
    __syncthreads();

    const float4* xq = (const float4*)xbuf;
    float acc0 = 0.f, acc1 = 0.f, acc2 = 0.f, acc3 = 0.f;
#pragma unroll 8
    for (int kk = 0; kk < H / 4; ++kk) {
        float4 x4 = xq[kk];
        acc0 += x4.x * W3[(4 * kk + 0) * H + c];
        acc1 += x4.y * W3[(4 * kk + 1) * H + c];
        acc2 += x4.z * W3[(4 * kk + 2) * H + c];
        acc3 += x4.w * W3[(4 * kk + 3) * H + c];
    }
    float p1 = fmaxf(0.f, (acc0 + acc1) + (acc2 + acc3) + b3[c]);
    __syncthreads();
    xbuf[c] = p1;
    __syncthreads();

    acc0 = 0.f; acc1 = 0.f; acc2 = 0.f; acc3 = 0.f;
#pragma unroll 8
    for (int kk = 0; kk < H / 4; ++kk) {
        float4 x4 = xq[kk];
        acc0 += x4.x * W4[(4 * kk + 0) * H + c];
        acc1 += x4.y * W4[(4 * kk + 1) * H + c];
        acc2 += x4.z * W4[(4 * kk + 2) * H + c];
        acc3 += x4.w * W4[(4 * kk + 3) * H + c];
    }
    float p2 = fmaxf(0.f, (acc0 + acc1) + (acc2 + acc3) + b4[c]);
    __syncthreads();
    xbuf[c] = p2;
    __syncthreads();

    if (c < IN) {
        float s = b5[c];
        for (int k = 0; k < H; ++k) s += xbuf[k] * W5[k * IN + c];
        predbuf[c] = s;
    }
    __syncthreads();
    if (c < IN) {
        int r = (c < 3) ? c : c - 3;
        int o = (c < 3) ? 0 : 3;
        float g = sR[r * 3 + 0] * predbuf[o + 0]
                + sR[r * 3 + 1] * predbuf[o + 1]
                + sR[r * 3 + 2] * predbuf[o + 2];
        out[bn * IN + c] = xi[c] + g;
    }
}

extern "C" void kernel_launch(void* const* d_in, const int* in_sizes, int n_in,
                              void* d_out, int out_size, void* d_ws, size_t ws_size,
                              hipStream_t stream) {
    const float* in = (const float*)d_in[0];
    const float* W1 = (const float*)d_in[1];
    const float* b1 = (const float*)d_in[2];
    const float* W2 = (const float*)d_in[3];
    const float* b2 = (const float*)d_in[4];
    const float* Wr = (const float*)d_in[5];
    const float* br = (const float*)d_in[6];
    const float* W3 = (const float*)d_in[7];
    const float* b3 = (const float*)d_in[8];
    const float* W4 = (const float*)d_in[9];
    const float* b4 = (const float*)d_in[10];
    const float* W5 = (const float*)d_in[11];
    const float* b5 = (const float*)d_in[12];
    const int* send = (const int*)d_in[13];
    const int* recv = (const int*)d_in[14];
    float* out = (float*)d_out;

    const int E = in_sizes[13];
    const int BN = in_sizes[0] / IN;   // B*N = 12800

    float* nR = (float*)d_ws;                 // BN*9
    float* ncv = nR + BN * 9;                 // BN*3
    int* cnt = (int*)(ncv + BN * 3);          // 128 ints
    int* rev = cnt + 128;                     // NNODE*128 ints

    hipMemsetAsync(cnt, 0, 128 * sizeof(int), stream);
    node_pre<<<(BN + 255) / 256, 256, 0, stream>>>(in, nR, ncv, BN);
    build_rev<<<(E + 255) / 256, 256, 0, stream>>>(send, recv, cnt, rev, E);
    edge_fused<<<BN, H, 0, stream>>>(in, W1, b1, W2, b2, Wr, br, W3, b3, W4, b4,
                                     W5, b5, nR, ncv, cnt, rev, out);
}

// Round 2
// 294.219 us; speedup vs baseline: 3.5145x; 3.5145x over previous
//
#include <hip/hip_runtime.h>
#include <math.h>

#define EPSF 1e-7f
constexpr int NNODE = 100;
constexpr int IN = 6;
constexpr int H = 128;
constexpr float INV_PI = 0.3183098861837907f;

__device__ __forceinline__ float clampf(float x, float lo, float hi) {
    return fminf(fmaxf(x, lo), hi);
}

// ---------------- Kernel A: per-node rotation R (row-major 3x3) + canon_vel = R^T v
__global__ void node_pre(const float* __restrict__ in, float* __restrict__ nR,
                         float* __restrict__ ncv, int total) {
    int i = blockIdx.x * blockDim.x + threadIdx.x;
    if (i >= total) return;
    const float* p = in + i * IN;
    float vx = p[3], vy = p[4], vz = p[5];
    float rho = sqrtf(vx * vx + vy * vy + vz * vz);
    float rxy = sqrtf(vx * vx + vy * vy);
    float ct, st;
    if (rxy > 1e-30f) { ct = vx / rxy; st = vy / rxy; } else { ct = 1.f; st = 0.f; }
    float cp = clampf(vz / (rho + EPSF), -1.f, 1.f);
    float sp = sqrtf(fmaxf(0.f, 1.f - cp * cp));
    float R0 = cp * ct, R1 = -st, R2 = sp * ct;
    float R3 = cp * st, R4 = ct,  R5 = sp * st;
    float R6 = -sp,     R7 = 0.f, R8 = cp;
    float* r = nR + i * 9;
    r[0] = R0; r[1] = R1; r[2] = R2;
    r[3] = R3; r[4] = R4; r[5] = R5;
    r[6] = R6; r[7] = R7; r[8] = R8;
    float* c = ncv + i * 3;
    c[0] = R0 * vx + R3 * vy + R6 * vz;
    c[1] = R1 * vx + R4 * vy + R7 * vz;
    c[2] = R2 * vx + R5 * vy + R8 * vz;
}

// ---------------- Kernel B: reverse index recv -> list of send nodes
__global__ void build_rev(const int* __restrict__ send, const int* __restrict__ recv,
                          int* __restrict__ cnt, int* __restrict__ rev, int E) {
    int e = blockIdx.x * blockDim.x + threadIdx.x;
    if (e >= E) return;
    int r = recv[e];
    int pos = atomicAdd(&cnt[r], 1);
    rev[r * 128 + pos] = send[e];
}

// ---------------- Kernel C: fused. KEY ALGEBRA: second edge-MLP layer is linear and
// aggregation is a sum, so  agg = (sum_e silu_e) @ W2 + deg*b2  — W2 applied ONCE
// per node, not per edge. Edge loop reduces to 12 FMA + silu per edge per channel.
__global__ __launch_bounds__(128)
void edge_fused(const float* __restrict__ in,
                const float* __restrict__ W1, const float* __restrict__ b1,
                const float* __restrict__ W2, const float* __restrict__ b2,
                const float* __restrict__ Wr, const float* __restrict__ br,
                const float* __restrict__ W3, const float* __restrict__ b3,
                const float* __restrict__ W4, const float* __restrict__ b4,
                const float* __restrict__ W5, const float* __restrict__ b5,
                const float* __restrict__ nR, const float* __restrict__ ncv,
                const int* __restrict__ cnt, const int* __restrict__ rev,
                float* __restrict__ out) {
    const int bn = blockIdx.x;
    const int b = bn / NNODE;
    const int n = bn - b * NNODE;
    const int c = threadIdx.x;

    __shared__ __align__(16) float ea[NNODE][12];   // per-edge unique features
    __shared__ __align__(16) float xbuf[H];         // hsum / aug / p buffers
    __shared__ float sR[9];
    __shared__ float predbuf[8];

    const float* rn = nR + bn * 9;
    float Rn[9];
#pragma unroll
    for (int k = 0; k < 9; ++k) Rn[k] = rn[k];
    if (c < 9) sR[c] = rn[c];

    const float* xi = in + bn * IN;
    float pix = xi[0], piy = xi[1], piz = xi[2];
    float cv0 = ncv[bn * 3 + 0], cv1 = ncv[bn * 3 + 1], cv2 = ncv[bn * 3 + 2];
    const int deg = cnt[n];

    // ---- phase 1: edge geometric features (thread t handles incoming edge t)
    if (c < deg) {
        int s = rev[n * 128 + c];
        const float* xj = in + (b * NNODE + s) * IN;
        float rel0 = xj[0] - pix, rel1 = xj[1] - piy, rel2 = xj[2] - piz;
        float vjx = xj[3], vjy = xj[4], vjz = xj[5];
        const float* rs = nR + (b * NNODE + s) * 9;
        float Rs0 = rs[0], Rs1 = rs[1], Rs2 = rs[2];
        float Rs3 = rs[3], Rs4 = rs[4], Rs5 = rs[5];
        float Rs6 = rs[6], Rs7 = rs[7], Rs8 = rs[8];
        float rr0 = Rn[0] * rel0 + Rn[3] * rel1 + Rn[6] * rel2;
        float rr1 = Rn[1] * rel0 + Rn[4] * rel1 + Rn[7] * rel2;
        float rr2 = Rn[2] * rel0 + Rn[5] * rel1 + Rn[8] * rel2;
        float ro00 = Rn[0] * Rs0 + Rn[3] * Rs3 + Rn[6] * Rs6;
        float ro10 = Rn[1] * Rs0 + Rn[4] * Rs3 + Rn[7] * Rs6;
        float ro20 = Rn[2] * Rs0 + Rn[5] * Rs3 + Rn[8] * Rs6;
        float ro21 = Rn[2] * Rs1 + Rn[5] * Rs4 + Rn[8] * Rs7;
        float ro22 = Rn[2] * Rs2 + Rn[5] * Rs5 + Rn[8] * Rs8;
        float e0 = atan2f(ro10, ro00) * INV_PI;
        float e1 = asinf(clampf(-ro20, -1.f, 1.f)) * INV_PI;
        float e2 = atan2f(ro21, ro22) * INV_PI;
        float dist = sqrtf(rel0 * rel0 + rel1 * rel1 + rel2 * rel2);
        float rho_e = sqrtf(rr0 * rr0 + rr1 * rr1 + rr2 * rr2);
        float th = atan2f(rr1, rr0);
        float ph = acosf(clampf(rr2 / (rho_e + EPSF), -1.f, 1.f));
        float rv0 = Rn[0] * vjx + Rn[3] * vjy + Rn[6] * vjz;
        float rv1 = Rn[1] * vjx + Rn[4] * vjy + Rn[7] * vjz;
        float rv2 = Rn[2] * vjx + Rn[5] * vjy + Rn[8] * vjz;
        float* d = ea[c];
        d[0] = rr0; d[1] = rr1; d[2] = rr2;
        d[3] = e0;  d[4] = e1;  d[5] = e2;
        d[6] = dist; d[7] = th; d[8] = ph;
        d[9] = rv0; d[10] = rv1; d[11] = rv2;
    }

    // W1 column c + folded bias (rel_feat = [0,0,0,cv]: rows 12-14 dead, 15-17 folded)
    float w1c[12];
#pragma unroll
    for (int k = 0; k < 12; ++k) w1c[k] = W1[k * H + c];
    float basec = b1[c] + cv0 * W1[15 * H + c] + cv1 * W1[16 * H + c] + cv2 * W1[17 * H + c];

    __syncthreads();

    // ---- phase 2: hsum[c] = sum_e silu(ea[e] . w1c + basec)  (registers only)
    float hsum = 0.f;
    for (int e = 0; e < deg; ++e) {
        const float4* eq = (const float4*)ea[e];
        float4 q0 = eq[0], q1 = eq[1], q2 = eq[2];
        float u0 = q0.x * w1c[0] + q0.y * w1c[1];
        float u1 = q0.z * w1c[2] + q0.w * w1c[3];
        float u2 = q1.x * w1c[4] + q1.y * w1c[5];
        float u3 = q1.z * w1c[6] + q1.w * w1c[7];
        float u4 = q2.x * w1c[8] + q2.y * w1c[9];
        float u5 = q2.z * w1c[10] + q2.w * w1c[11];
        float hp = basec + ((u0 + u1) + (u2 + u3)) + (u4 + u5);
        hsum += hp / (1.f + __expf(-hp));   // silu
    }
    xbuf[c] = hsum;
    __syncthreads();

    // ---- phase 3: agg_c = (hsum @ W2)[c] / deg + b2[c]; then node MLP
    const float4* xq = (const float4*)xbuf;
    float acc0 = 0.f, acc1 = 0.f, acc2 = 0.f, acc3 = 0.f;
#pragma unroll 8
    for (int kk = 0; kk < H / 4; ++kk) {
        float4 x4 = xq[kk];
        acc0 += x4.x * W2[(4 * kk + 0) * H + c];
        acc1 += x4.y * W2[(4 * kk + 1) * H + c];
        acc2 += x4.z * W2[(4 * kk + 2) * H + c];
        acc3 += x4.w * W2[(4 * kk + 3) * H + c];
    }
    int degc = deg < 1 ? 1 : deg;
    float invdeg = 1.f / (float)degc;
    float aug = ((acc0 + acc1) + (acc2 + acc3)) * invdeg + b2[c]
              + cv0 * Wr[3 * H + c] + cv1 * Wr[4 * H + c] + cv2 * Wr[5 * H + c] + br[c];
    __syncthreads();
    xbuf[c] = aug;
    __syncthreads();

    acc0 = 0.f; acc1 = 0.f; acc2 = 0.f; acc3 = 0.f;
#pragma unroll 8
    for (int kk = 0; kk < H / 4; ++kk) {
        float4 x4 = xq[kk];
        acc0 += x4.x * W3[(4 * kk + 0) * H + c];
        acc1 += x4.y * W3[(4 * kk + 1) * H + c];
        acc2 += x4.z * W3[(4 * kk + 2) * H + c];
        acc3 += x4.w * W3[(4 * kk + 3) * H + c];
    }
    float p1 = fmaxf(0.f, (acc0 + acc1) + (acc2 + acc3) + b3[c]);
    __syncthreads();
    xbuf[c] = p1;
    __syncthreads();

    acc0 = 0.f; acc1 = 0.f; acc2 = 0.f; acc3 = 0.f;
#pragma unroll 8
    for (int kk = 0; kk < H / 4; ++kk) {
        float4 x4 = xq[kk];
        acc0 += x4.x * W4[(4 * kk + 0) * H + c];
        acc1 += x4.y * W4[(4 * kk + 1) * H + c];
        acc2 += x4.z * W4[(4 * kk + 2) * H + c];
        acc3 += x4.w * W4[(4 * kk + 3) * H + c];
    }
    float p2 = fmaxf(0.f, (acc0 + acc1) + (acc2 + acc3) + b4[c]);
    __syncthreads();
    xbuf[c] = p2;
    __syncthreads();

    if (c < IN) {
        float s = b5[c];
        for (int k = 0; k < H; ++k) s += xbuf[k] * W5[k * IN + c];
        predbuf[c] = s;
    }
    __syncthreads();
    if (c < IN) {
        int r = (c < 3) ? c : c - 3;
        int o = (c < 3) ? 0 : 3;
        float g = sR[r * 3 + 0] * predbuf[o + 0]
                + sR[r * 3 + 1] * predbuf[o + 1]
                + sR[r * 3 + 2] * predbuf[o + 2];
        out[bn * IN + c] = xi[c] + g;
    }
}

extern "C" void kernel_launch(void* const* d_in, const int* in_sizes, int n_in,
                              void* d_out, int out_size, void* d_ws, size_t ws_size,
                              hipStream_t stream) {
    const float* in = (const float*)d_in[0];
    const float* W1 = (const float*)d_in[1];
    const float* b1 = (const float*)d_in[2];
    const float* W2 = (const float*)d_in[3];
    const float* b2 = (const float*)d_in[4];
    const float* Wr = (const float*)d_in[5];
    const float* br = (const float*)d_in[6];
    const float* W3 = (const float*)d_in[7];
    const float* b3 = (const float*)d_in[8];
    const float* W4 = (const float*)d_in[9];
    const float* b4 = (const float*)d_in[10];
    const float* W5 = (const float*)d_in[11];
    const float* b5 = (const float*)d_in[12];
    const int* send = (const int*)d_in[13];
    const int* recv = (const int*)d_in[14];
    float* out = (float*)d_out;

    const int E = in_sizes[13];
    const int BN = in_sizes[0] / IN;   // B*N = 12800

    float* nR = (float*)d_ws;                 // BN*9
    float* ncv = nR + BN * 9;                 // BN*3
    int* cnt = (int*)(ncv + BN * 3);          // 128 ints
    int* rev = cnt + 128;                     // NNODE*128 ints

    hipMemsetAsync(cnt, 0, 128 * sizeof(int), stream);
    node_pre<<<(BN + 255) / 256, 256, 0, stream>>>(in, nR, ncv, BN);
    build_rev<<<(E + 255) / 256, 256, 0, stream>>>(send, recv, cnt, rev, E);
    edge_fused<<<BN, H, 0, stream>>>(in, W1, b1, W2, b2, Wr, br, W3, b3, W4, b4,
                                     W5, b5, nR, ncv, cnt, rev, out);
}

// Round 3
// 229.799 us; speedup vs baseline: 4.4997x; 1.2803x over previous
//
#include <hip/hip_runtime.h>
#include <math.h>

#define EPSF 1e-7f
constexpr int NNODE = 100;
constexpr int IN = 6;
constexpr int H = 128;
constexpr float INV_PI = 0.3183098861837907f;

typedef float v2f __attribute__((ext_vector_type(2)));

__device__ __forceinline__ float clampf(float x, float lo, float hi) {
    return fminf(fmaxf(x, lo), hi);
}

// fast sigmoid: 1/(1+e^-x) with native exp + native rcp (1-ulp each)
__device__ __forceinline__ float fast_sig(float x) {
    return __builtin_amdgcn_rcpf(1.f + __expf(-x));
}

// compute row-major 3x3 rotation from velocity (algebraic form of the
// cos/sin(atan2/arccos) construction in the reference)
__device__ __forceinline__ void vel_to_R(float vx, float vy, float vz, float* R) {
    float rho = sqrtf(vx * vx + vy * vy + vz * vz);
    float rxy2 = vx * vx + vy * vy;
    float rxy = sqrtf(rxy2);
    float inv = __builtin_amdgcn_rcpf(rxy);
    bool big = rxy > 1e-30f;
    float ct = big ? vx * inv : 1.f;
    float st = big ? vy * inv : 0.f;
    float cp = clampf(vz * __builtin_amdgcn_rcpf(rho + EPSF), -1.f, 1.f);
    float sp = sqrtf(fmaxf(0.f, 1.f - cp * cp));
    R[0] = cp * ct; R[1] = -st; R[2] = sp * ct;
    R[3] = cp * st; R[4] = ct;  R[5] = sp * st;
    R[6] = -sp;     R[7] = 0.f; R[8] = cp;
}

// ---------------- Kernel A: reverse index recv -> list of send nodes
__global__ void build_rev(const int* __restrict__ send, const int* __restrict__ recv,
                          int* __restrict__ cnt, int* __restrict__ rev, int E) {
    int e = blockIdx.x * blockDim.x + threadIdx.x;
    if (e >= E) return;
    int r = recv[e];
    int pos = atomicAdd(&cnt[r], 1);
    rev[r * 128 + pos] = send[e];
}

// ---------------- Kernel B: fully fused.
//  agg = (sum_e silu_e) @ W2 algebra (R2) + packed-fp32 edge pairs (R3).
//  ea2f layout: pair p, feature k -> ea2f[p*24 + 2k + {0,1}] so a float4 load
//  gives {f_k.e, f_k.o, f_{k+1}.e, f_{k+1}.o} = two v2f operands in place.
__global__ __launch_bounds__(128)
void edge_fused(const float* __restrict__ in,
                const float* __restrict__ W1, const float* __restrict__ b1,
                const float* __restrict__ W2, const float* __restrict__ b2,
                const float* __restrict__ Wr, const float* __restrict__ br,
                const float* __restrict__ W3, const float* __restrict__ b3,
                const float* __restrict__ W4, const float* __restrict__ b4,
                const float* __restrict__ W5, const float* __restrict__ b5,
                const int* __restrict__ cnt, const int* __restrict__ rev,
                float* __restrict__ out) {
    const int bn = blockIdx.x;
    const int b = bn / NNODE;
    const int n = bn - b * NNODE;
    const int c = threadIdx.x;

    __shared__ __align__(16) float ea2f[64 * 24];   // 50 pairs x 12 features x 2
    __shared__ __align__(16) float xbuf[H];
    __shared__ float pb[16][8];
    __shared__ float predbuf[8];

    // ---- phase 0: own-node rotation + canon_vel (all threads, registers)
    const float* xi = in + bn * IN;
    float pix = xi[0], piy = xi[1], piz = xi[2];
    float vix = xi[3], viy = xi[4], viz = xi[5];
    float Rn[9];
    vel_to_R(vix, viy, viz, Rn);
    float cv0 = Rn[0] * vix + Rn[3] * viy + Rn[6] * viz;
    float cv1 = Rn[1] * vix + Rn[4] * viy + Rn[7] * viz;
    float cv2 = Rn[2] * vix + Rn[5] * viy + Rn[8] * viz;
    const int deg = cnt[n];

    // ---- phase 1: edge geometric features (thread t -> incoming edge t)
    if (c < deg) {
        int s = rev[n * 128 + c];
        const float* xj = in + (b * NNODE + s) * IN;
        float rel0 = xj[0] - pix, rel1 = xj[1] - piy, rel2 = xj[2] - piz;
        float vjx = xj[3], vjy = xj[4], vjz = xj[5];
        float Rs[9];
        vel_to_R(vjx, vjy, vjz, Rs);
        float rr0 = Rn[0] * rel0 + Rn[3] * rel1 + Rn[6] * rel2;
        float rr1 = Rn[1] * rel0 + Rn[4] * rel1 + Rn[7] * rel2;
        float rr2 = Rn[2] * rel0 + Rn[5] * rel1 + Rn[8] * rel2;
        float ro00 = Rn[0] * Rs[0] + Rn[3] * Rs[3] + Rn[6] * Rs[6];
        float ro10 = Rn[1] * Rs[0] + Rn[4] * Rs[3] + Rn[7] * Rs[6];
        float ro20 = Rn[2] * Rs[0] + Rn[5] * Rs[3] + Rn[8] * Rs[6];
        float ro21 = Rn[2] * Rs[1] + Rn[5] * Rs[4] + Rn[8] * Rs[7];
        float ro22 = Rn[2] * Rs[2] + Rn[5] * Rs[5] + Rn[8] * Rs[8];
        float d[12];
        d[0] = rr0; d[1] = rr1; d[2] = rr2;
        d[3] = atan2f(ro10, ro00) * INV_PI;
        d[4] = asinf(clampf(-ro20, -1.f, 1.f)) * INV_PI;
        d[5] = atan2f(ro21, ro22) * INV_PI;
        d[6] = sqrtf(rel0 * rel0 + rel1 * rel1 + rel2 * rel2);
        float rho_e = sqrtf(rr0 * rr0 + rr1 * rr1 + rr2 * rr2);
        d[7] = atan2f(rr1, rr0);
        d[8] = acosf(clampf(rr2 / (rho_e + EPSF), -1.f, 1.f));
        d[9]  = Rn[0] * vjx + Rn[3] * vjy + Rn[6] * vjz;
        d[10] = Rn[1] * vjx + Rn[4] * vjy + Rn[7] * vjz;
        d[11] = Rn[2] * vjx + Rn[5] * vjy + Rn[8] * vjz;
        float* dst = ea2f + (c >> 1) * 24 + (c & 1);
#pragma unroll
        for (int k = 0; k < 12; ++k) dst[2 * k] = d[k];
    }

    // W1 column c as splatted v2f pairs + folded bias
    v2f w1c2[12];
#pragma unroll
    for (int k = 0; k < 12; ++k) {
        float w = W1[k * H + c];
        w1c2[k] = (v2f){w, w};
    }
    float basec = b1[c] + cv0 * W1[15 * H + c] + cv1 * W1[16 * H + c] + cv2 * W1[17 * H + c];
    v2f basec2 = (v2f){basec, basec};

    __syncthreads();

    // ---- phase 2: hsum[c] = sum_e silu(ea[e].w1c + basec), edge PAIRS in pk-fp32
    v2f hsum2 = (v2f){0.f, 0.f};
    const int npair = deg >> 1;
    for (int p = 0; p < npair; ++p) {
        const float4* eq = (const float4*)(ea2f + p * 24);
        float4 q0 = eq[0], q1 = eq[1], q2 = eq[2], q3 = eq[3], q4 = eq[4], q5 = eq[5];
        v2f acca = (v2f){q0.x, q0.y} * w1c2[0];
        acca += (v2f){q0.z, q0.w} * w1c2[1];
        acca += (v2f){q1.x, q1.y} * w1c2[2];
        acca += (v2f){q1.z, q1.w} * w1c2[3];
        v2f accb = (v2f){q2.x, q2.y} * w1c2[4];
        accb += (v2f){q2.z, q2.w} * w1c2[5];
        accb += (v2f){q3.x, q3.y} * w1c2[6];
        accb += (v2f){q3.z, q3.w} * w1c2[7];
        v2f accc = (v2f){q4.x, q4.y} * w1c2[8];
        accc += (v2f){q4.z, q4.w} * w1c2[9];
        accc += (v2f){q5.x, q5.y} * w1c2[10];
        accc += (v2f){q5.z, q5.w} * w1c2[11];
        v2f hp = basec2 + acca + (accb + accc);
        v2f g = (v2f){fast_sig(hp.x), fast_sig(hp.y)};
        hsum2 += hp * g;
    }
    float hsum = hsum2.x + hsum2.y;
    if (deg & 1) {
        const float* ef = ea2f + npair * 24;
        float hp = basec;
#pragma unroll
        for (int k = 0; k < 12; ++k) hp = fmaf(ef[2 * k], w1c2[k].x, hp);
        hsum = fmaf(hp, fast_sig(hp), hsum);
    }
    xbuf[c] = hsum;
    __syncthreads();

    // ---- phase 3: agg = (hsum @ W2)/deg + b2 + rel_feat@Wr + br; then node MLP
    const float4* xq = (const float4*)xbuf;
    {
        const float* w = W2 + c;
        float acc0 = 0.f, acc1 = 0.f, acc2 = 0.f, acc3 = 0.f;
#pragma unroll 8
        for (int kk = 0; kk < H / 4; ++kk) {
            float4 x4 = xq[kk];
            acc0 = fmaf(x4.x, w[0], acc0);
            acc1 = fmaf(x4.y, w[H], acc1);
            acc2 = fmaf(x4.z, w[2 * H], acc2);
            acc3 = fmaf(x4.w, w[3 * H], acc3);
            w += 4 * H;
        }
        int degc = deg < 1 ? 1 : deg;
        float invdeg = __builtin_amdgcn_rcpf((float)degc);
        float aug = ((acc0 + acc1) + (acc2 + acc3)) * invdeg + b2[c]
                  + cv0 * Wr[3 * H + c] + cv1 * Wr[4 * H + c] + cv2 * Wr[5 * H + c] + br[c];
        __syncthreads();
        xbuf[c] = aug;
    }
    __syncthreads();
    {
        const float* w = W3 + c;
        float acc0 = 0.f, acc1 = 0.f, acc2 = 0.f, acc3 = 0.f;
#pragma unroll 8
        for (int kk = 0; kk < H / 4; ++kk) {
            float4 x4 = xq[kk];
            acc0 = fmaf(x4.x, w[0], acc0);
            acc1 = fmaf(x4.y, w[H], acc1);
            acc2 = fmaf(x4.z, w[2 * H], acc2);
            acc3 = fmaf(x4.w, w[3 * H], acc3);
            w += 4 * H;
        }
        float p1 = fmaxf(0.f, (acc0 + acc1) + (acc2 + acc3) + b3[c]);
        __syncthreads();
        xbuf[c] = p1;
    }
    __syncthreads();
    {
        const float* w = W4 + c;
        float acc0 = 0.f, acc1 = 0.f, acc2 = 0.f, acc3 = 0.f;
#pragma unroll 8
        for (int kk = 0; kk < H / 4; ++kk) {
            float4 x4 = xq[kk];
            acc0 = fmaf(x4.x, w[0], acc0);
            acc1 = fmaf(x4.y, w[H], acc1);
            acc2 = fmaf(x4.z, w[2 * H], acc2);
            acc3 = fmaf(x4.w, w[3 * H], acc3);
            w += 4 * H;
        }
        float p2 = fmaxf(0.f, (acc0 + acc1) + (acc2 + acc3) + b4[c]);
        __syncthreads();
        xbuf[c] = p2;
    }
    __syncthreads();

    // ---- W5 (128x6) distributed over 96 threads: thread -> (output o, k-slice)
    if (c < 96) {
        int o = c >> 4;
        int kb = (c & 15) << 3;
        const float* wrow = W5 + kb * IN + o;
        float s = 0.f;
#pragma unroll
        for (int j = 0; j < 8; ++j) s = fmaf(xbuf[kb + j], wrow[j * IN], s);
        pb[c & 15][o] = s;
    }
    __syncthreads();
    if (c < IN) {
        float s = b5[c];
#pragma unroll
        for (int j = 0; j < 16; ++j) s += pb[j][c];
        predbuf[c] = s;
    }
    __syncthreads();
    if (c < IN) {
        int r = (c < 3) ? c : c - 3;
        int o = (c < 3) ? 0 : 3;
        float g = Rn[r * 3 + 0] * predbuf[o + 0]
                + Rn[r * 3 + 1] * predbuf[o + 1]
                + Rn[r * 3 + 2] * predbuf[o + 2];
        out[bn * IN + c] = xi[c] + g;
    }
}

extern "C" void kernel_launch(void* const* d_in, const int* in_sizes, int n_in,
                              void* d_out, int out_size, void* d_ws, size_t ws_size,
                              hipStream_t stream) {
    const float* in = (const float*)d_in[0];
    const float* W1 = (const float*)d_in[1];
    const float* b1 = (const float*)d_in[2];
    const float* W2 = (const float*)d_in[3];
    const float* b2 = (const float*)d_in[4];
    const float* Wr = (const float*)d_in[5];
    const float* br = (const float*)d_in[6];
    const float* W3 = (const float*)d_in[7];
    const float* b3 = (const float*)d_in[8];
    const float* W4 = (const float*)d_in[9];
    const float* b4 = (const float*)d_in[10];
    const float* W5 = (const float*)d_in[11];
    const float* b5 = (const float*)d_in[12];
    const int* send = (const int*)d_in[13];
    const int* recv = (const int*)d_in[14];
    float* out = (float*)d_out;

    const int E = in_sizes[13];
    const int BN = in_sizes[0] / IN;   // B*N = 12800

    int* cnt = (int*)d_ws;            // 128 ints
    int* rev = cnt + 128;             // NNODE*128 ints

    hipMemsetAsync(cnt, 0, 128 * sizeof(int), stream);
    build_rev<<<(E + 255) / 256, 256, 0, stream>>>(send, recv, cnt, rev, E);
    edge_fused<<<BN, H, 0, stream>>>(in, W1, b1, W2, b2, Wr, br, W3, b3, W4, b4,
                                     W5, b5, cnt, rev, out);
}

// Round 5
// 176.115 us; speedup vs baseline: 5.8713x; 1.3048x over previous
//
#include <hip/hip_runtime.h>
#include <math.h>

#define EPSF 1e-7f
constexpr int NN  = 100;   // nodes per graph
constexpr int DEG = 99;    // fully-connected: deg = NN-1 for every node
constexpr int IN  = 6;
constexpr int H   = 128;
constexpr int G   = 4;     // nodes per block
constexpr float INV_PI = 0.3183098861837907f;

typedef __attribute__((ext_vector_type(8))) short short8;   // 8 bf16 (4 VGPR)
typedef __attribute__((ext_vector_type(4))) float f32x4;

__device__ __forceinline__ float clampf(float x, float lo, float hi) {
    return fminf(fmaxf(x, lo), hi);
}
__device__ __forceinline__ float fast_sig(float x) {
    return __builtin_amdgcn_rcpf(1.f + __expf(-x));
}
__device__ __forceinline__ unsigned short f2bf(float x) {   // RNE fp32->bf16
    unsigned int u = __float_as_uint(x);
    u = (u + 0x7FFFu + ((u >> 16) & 1u)) >> 16;
    return (unsigned short)u;
}
__device__ __forceinline__ void vel_to_R(float vx, float vy, float vz, float* R) {
    float rho = sqrtf(vx * vx + vy * vy + vz * vz);
    float rxy = sqrtf(vx * vx + vy * vy);
    float inv = __builtin_amdgcn_rcpf(rxy);
    bool big = rxy > 1e-30f;
    float ct = big ? vx * inv : 1.f;
    float st = big ? vy * inv : 0.f;
    float cp = clampf(vz * __builtin_amdgcn_rcpf(rho + EPSF), -1.f, 1.f);
    float sp = sqrtf(fmaxf(0.f, 1.f - cp * cp));
    R[0] = cp * ct; R[1] = -st; R[2] = sp * ct;
    R[3] = cp * st; R[4] = ct;  R[5] = sp * st;
    R[6] = -sp;     R[7] = 0.f; R[8] = cp;
}

// One block = 4 consecutive (b,n) nodes. Edge layer via bf16 MFMA (K=32, 12 live),
// fragments staged in TYPED LDS arrays (short8 written AND read as short8 —
// no mixed-type aliasing, no char-blob casts; R4's replay divergence traced to
// TBAA-unsafe mixed int4/short8 access of one aliased blob).
// agg = (sum_e silu_e) @ W2 / 99 + b2 (second edge layer folded). Node MLP
// batched over the 4 nodes so W2/W3/W4 are fetched once per block.
__global__ __launch_bounds__(128)
void locs_fused(const float* __restrict__ in,
                const float* __restrict__ W1, const float* __restrict__ b1,
                const float* __restrict__ W2, const float* __restrict__ b2,
                const float* __restrict__ Wr, const float* __restrict__ br,
                const float* __restrict__ W3, const float* __restrict__ b3,
                const float* __restrict__ W4, const float* __restrict__ b4,
                const float* __restrict__ W5, const float* __restrict__ b5,
                float* __restrict__ out) {
    __shared__ short8 eaA[7 * 64];     // A fragments: 7 edge-tiles x 64 lanes
    __shared__ short8 w1B[8 * 64];     // B fragments: 8 channel-tiles x 64 lanes
    __shared__ float baseF[G][H];      // folded bias per (node, channel)
    __shared__ float xF[G][H];         // hsum / aug / p buffers
    __shared__ float rmF[G][16];       // R(9) + cv(3) per node
    __shared__ float pbF[G][96];       // W5 partial sums
    __shared__ float predF[G][8];      // final pred (6 used)

    const int tid = threadIdx.x;
    const int L   = tid & 63;
    const int wv  = tid >> 6;
    const int q   = L >> 4;
    const int lm  = L & 15;
    const int bn0 = blockIdx.x * G;

    // ---- setup: zero A-fragment buffer (pad rows / pad-k stay zero this launch)
    {
        short8 z = 0;
#pragma unroll
        for (int i = 0; i < 4; ++i) {
            int idx = tid + i * 128;
            if (idx < 7 * 64) eaA[idx] = z;
        }
    }
    // ---- setup: R + canon_vel for the 4 nodes (threads 0..3)
    if (tid < G) {
        const float* xi = in + (bn0 + tid) * IN;
        float R[9];
        vel_to_R(xi[3], xi[4], xi[5], R);
#pragma unroll
        for (int k = 0; k < 9; ++k) rmF[tid][k] = R[k];
        rmF[tid][9]  = R[0] * xi[3] + R[3] * xi[4] + R[6] * xi[5];
        rmF[tid][10] = R[1] * xi[3] + R[4] * xi[4] + R[7] * xi[5];
        rmF[tid][11] = R[2] * xi[3] + R[5] * xi[4] + R[8] * xi[5];
    }
    // ---- setup: W1 -> bf16 B-fragments (thread c = channel), zero pad-k
    {
        int c = tid;
        int nt = c >> 4, lc = c & 15;
        short8 lo = 0, hi = 0, zz = 0;
#pragma unroll
        for (int k = 0; k < 8; ++k) lo[k] = (short)f2bf(W1[k * H + c]);
#pragma unroll
        for (int k = 0; k < 4; ++k) hi[k] = (short)f2bf(W1[(8 + k) * H + c]);
        w1B[nt * 64 +      lc] = lo;
        w1B[nt * 64 + 16 + lc] = hi;
        w1B[nt * 64 + 32 + lc] = zz;
        w1B[nt * 64 + 48 + lc] = zz;
    }
    __syncthreads();

    // folded bias per (g, channel): b1 + cv_g . W1[15..17]
    {
        float w15 = W1[15 * H + tid], w16 = W1[16 * H + tid], w17 = W1[17 * H + tid];
        float b1c = b1[tid];
#pragma unroll
        for (int g = 0; g < G; ++g)
            baseF[g][tid] = b1c + rmF[g][9] * w15 + rmF[g][10] * w16 + rmF[g][11] * w17;
    }
    // B fragments -> registers (this wave's 4 channel-tiles)
    short8 bfr[4];
#pragma unroll
    for (int i = 0; i < 4; ++i) bfr[i] = w1B[(wv * 4 + i) * 64 + L];

    // ---- per-node edge phase
    for (int g = 0; g < G; ++g) {
        __syncthreads();   // prior iteration's MFMA reads of eaA complete
        int bng = bn0 + g;
        int bB = bng / NN;
        int nG = bng - bB * NN;
        if (tid < DEG) {
            int s = tid < nG ? tid : tid + 1;          // implicit ~eye edge list
            float Rn[9];
#pragma unroll
            for (int k = 0; k < 9; ++k) Rn[k] = rmF[g][k];
            const float* xi = in + bng * IN;
            const float* xj = in + (bB * NN + s) * IN;
            float rel0 = xj[0] - xi[0], rel1 = xj[1] - xi[1], rel2 = xj[2] - xi[2];
            float vjx = xj[3], vjy = xj[4], vjz = xj[5];
            float Rs[9];
            vel_to_R(vjx, vjy, vjz, Rs);
            float rr0 = Rn[0] * rel0 + Rn[3] * rel1 + Rn[6] * rel2;
            float rr1 = Rn[1] * rel0 + Rn[4] * rel1 + Rn[7] * rel2;
            float rr2 = Rn[2] * rel0 + Rn[5] * rel1 + Rn[8] * rel2;
            float ro00 = Rn[0] * Rs[0] + Rn[3] * Rs[3] + Rn[6] * Rs[6];
            float ro10 = Rn[1] * Rs[0] + Rn[4] * Rs[3] + Rn[7] * Rs[6];
            float ro20 = Rn[2] * Rs[0] + Rn[5] * Rs[3] + Rn[8] * Rs[6];
            float ro21 = Rn[2] * Rs[1] + Rn[5] * Rs[4] + Rn[8] * Rs[7];
            float ro22 = Rn[2] * Rs[2] + Rn[5] * Rs[5] + Rn[8] * Rs[8];
            float d[12];
            d[0] = rr0; d[1] = rr1; d[2] = rr2;
            d[3] = atan2f(ro10, ro00) * INV_PI;
            d[4] = asinf(clampf(-ro20, -1.f, 1.f)) * INV_PI;
            d[5] = atan2f(ro21, ro22) * INV_PI;
            d[6] = sqrtf(rel0 * rel0 + rel1 * rel1 + rel2 * rel2);
            float rho_e = sqrtf(rr0 * rr0 + rr1 * rr1 + rr2 * rr2);
            d[7] = atan2f(rr1, rr0);
            d[8] = acosf(clampf(rr2 / (rho_e + EPSF), -1.f, 1.f));
            d[9]  = Rn[0] * vjx + Rn[3] * vjy + Rn[6] * vjz;
            d[10] = Rn[1] * vjx + Rn[4] * vjy + Rn[7] * vjz;
            d[11] = Rn[2] * vjx + Rn[5] * vjy + Rn[8] * vjz;
            short8 lo = 0, hi = 0;
#pragma unroll
            for (int k = 0; k < 8; ++k) lo[k] = (short)f2bf(d[k]);
#pragma unroll
            for (int k = 0; k < 4; ++k) hi[k] = (short)f2bf(d[8 + k]);
            int t = tid >> 4, m = tid & 15;
            eaA[t * 64 +      m] = lo;
            eaA[t * 64 + 16 + m] = hi;   // k=12..15 lanes stay zero (hi[4..7]=0)
        }
        __syncthreads();

        // MFMA + silu + row-accumulate.  D row = edge q*4+r within tile, col = channel.
        float bs[4], part[4] = {0.f, 0.f, 0.f, 0.f};
#pragma unroll
        for (int i = 0; i < 4; ++i) bs[i] = baseF[g][wv * 64 + i * 16 + lm];
        f32x4 zc = {0.f, 0.f, 0.f, 0.f};
#pragma unroll
        for (int t = 0; t < 6; ++t) {   // full tiles: edges t*16 .. t*16+15
            short8 a = eaA[t * 64 + L];
            f32x4 d0 = __builtin_amdgcn_mfma_f32_16x16x32_bf16(a, bfr[0], zc, 0, 0, 0);
            f32x4 d1 = __builtin_amdgcn_mfma_f32_16x16x32_bf16(a, bfr[1], zc, 0, 0, 0);
            f32x4 d2 = __builtin_amdgcn_mfma_f32_16x16x32_bf16(a, bfr[2], zc, 0, 0, 0);
            f32x4 d3 = __builtin_amdgcn_mfma_f32_16x16x32_bf16(a, bfr[3], zc, 0, 0, 0);
#pragma unroll
            for (int r = 0; r < 4; ++r) {
                float v0 = d0[r] + bs[0]; part[0] += v0 * fast_sig(v0);
                float v1 = d1[r] + bs[1]; part[1] += v1 * fast_sig(v1);
                float v2 = d2[r] + bs[2]; part[2] += v2 * fast_sig(v2);
                float v3 = d3[r] + bs[3]; part[3] += v3 * fast_sig(v3);
            }
        }
        {   // tail tile t=6: edges 96..98 valid only (q==0, r<3)
            short8 a = eaA[6 * 64 + L];
            f32x4 d0 = __builtin_amdgcn_mfma_f32_16x16x32_bf16(a, bfr[0], zc, 0, 0, 0);
            f32x4 d1 = __builtin_amdgcn_mfma_f32_16x16x32_bf16(a, bfr[1], zc, 0, 0, 0);
            f32x4 d2 = __builtin_amdgcn_mfma_f32_16x16x32_bf16(a, bfr[2], zc, 0, 0, 0);
            f32x4 d3 = __builtin_amdgcn_mfma_f32_16x16x32_bf16(a, bfr[3], zc, 0, 0, 0);
            bool ok = (q == 0);
#pragma unroll
            for (int r = 0; r < 3; ++r) {
                float v0 = d0[r] + bs[0]; part[0] += ok ? v0 * fast_sig(v0) : 0.f;
                float v1 = d1[r] + bs[1]; part[1] += ok ? v1 * fast_sig(v1) : 0.f;
                float v2 = d2[r] + bs[2]; part[2] += ok ? v2 * fast_sig(v2) : 0.f;
                float v3 = d3[r] + bs[3]; part[3] += ok ? v3 * fast_sig(v3) : 0.f;
            }
        }
        // reduce over the 4 q-groups (lanes L, L^16, L^32, L^48)
#pragma unroll
        for (int i = 0; i < 4; ++i) {
            float v = part[i];
            v += __shfl_xor(v, 16, 64);
            v += __shfl_xor(v, 32, 64);
            if (L < 16) xF[g][wv * 64 + i * 16 + L] = v;
        }
    }
    __syncthreads();

    // ---- node MLP, batched over the 4 nodes (W fetched once per block)
    float b2c = b2[tid], brc = br[tid], b3c = b3[tid], b4c = b4[tid];
    float wr3 = Wr[3 * H + tid], wr4 = Wr[4 * H + tid], wr5 = Wr[5 * H + tid];

    {   // layer: agg = hsum @ W2 / 99 + b2 ; aug = agg + cv.Wr + br
        float acc0 = 0.f, acc1 = 0.f, acc2 = 0.f, acc3 = 0.f;
        const float* wp = W2 + tid;
        for (int kk = 0; kk < 32; ++kk) {
            float w0 = wp[0], w1 = wp[H], w2 = wp[2 * H], w3 = wp[3 * H];
            f32x4 x0 = *(const f32x4*)&xF[0][kk * 4];
            f32x4 x1 = *(const f32x4*)&xF[1][kk * 4];
            f32x4 x2 = *(const f32x4*)&xF[2][kk * 4];
            f32x4 x3 = *(const f32x4*)&xF[3][kk * 4];
            acc0 += w0 * x0.x + w1 * x0.y + w2 * x0.z + w3 * x0.w;
            acc1 += w0 * x1.x + w1 * x1.y + w2 * x1.z + w3 * x1.w;
            acc2 += w0 * x2.x + w1 * x2.y + w2 * x2.z + w3 * x2.w;
            acc3 += w0 * x3.x + w1 * x3.y + w2 * x3.z + w3 * x3.w;
            wp += 4 * H;
        }
        __syncthreads();
        float acc[4] = {acc0, acc1, acc2, acc3};
#pragma unroll
        for (int g = 0; g < G; ++g)
            xF[g][tid] = acc[g] * (1.f / 99.f) + b2c
                       + rmF[g][9] * wr3 + rmF[g][10] * wr4 + rmF[g][11] * wr5 + brc;
        __syncthreads();
    }
#pragma unroll
    for (int layer = 0; layer < 2; ++layer) {   // relu(x @ W3/W4 + b)
        const float* W = (layer == 0) ? W3 : W4;
        float bb = (layer == 0) ? b3c : b4c;
        float acc0 = 0.f, acc1 = 0.f, acc2 = 0.f, acc3 = 0.f;
        const float* wp = W + tid;
        for (int kk = 0; kk < 32; ++kk) {
            float w0 = wp[0], w1 = wp[H], w2 = wp[2 * H], w3 = wp[3 * H];
            f32x4 x0 = *(const f32x4*)&xF[0][kk * 4];
            f32x4 x1 = *(const f32x4*)&xF[1][kk * 4];
            f32x4 x2 = *(const f32x4*)&xF[2][kk * 4];
            f32x4 x3 = *(const f32x4*)&xF[3][kk * 4];
            acc0 += w0 * x0.x + w1 * x0.y + w2 * x0.z + w3 * x0.w;
            acc1 += w0 * x1.x + w1 * x1.y + w2 * x1.z + w3 * x1.w;
            acc2 += w0 * x2.x + w1 * x2.y + w2 * x2.z + w3 * x2.w;
            acc3 += w0 * x3.x + w1 * x3.y + w2 * x3.z + w3 * x3.w;
            wp += 4 * H;
        }
        __syncthreads();
        xF[0][tid] = fmaxf(0.f, acc0 + bb);
        xF[1][tid] = fmaxf(0.f, acc1 + bb);
        xF[2][tid] = fmaxf(0.f, acc2 + bb);
        xF[3][tid] = fmaxf(0.f, acc3 + bb);
        __syncthreads();
    }

    // ---- pred = p2 @ W5 + b5 (96 threads x 8-k slices), then rotate + residual
    if (tid < 96) {
        int o = tid >> 4, sl = tid & 15, kb = sl * 8;
        float w5[8];
#pragma unroll
        for (int j = 0; j < 8; ++j) w5[j] = W5[(kb + j) * IN + o];
#pragma unroll
        for (int g = 0; g < G; ++g) {
            float s = 0.f;
#pragma unroll
            for (int j = 0; j < 8; ++j) s = fmaf(xF[g][kb + j], w5[j], s);
            pbF[g][sl * 6 + o] = s;
        }
    }
    __syncthreads();
    if (tid < 24) {
        int g = tid / 6, o = tid - g * 6;
        float s = b5[o];
#pragma unroll
        for (int sl = 0; sl < 16; ++sl) s += pbF[g][sl * 6 + o];
        predF[g][o] = s;
    }
    __syncthreads();
    if (tid < 24) {
        int g = tid / 6, o = tid - g * 6;
        int r = (o < 3) ? o : o - 3;
        int off = (o < 3) ? 0 : 3;
        float gl = rmF[g][r * 3 + 0] * predF[g][off + 0]
                 + rmF[g][r * 3 + 1] * predF[g][off + 1]
                 + rmF[g][r * 3 + 2] * predF[g][off + 2];
        int bng = bn0 + g;
        out[bng * IN + o] = in[bng * IN + o] + gl;
    }
}

extern "C" void kernel_launch(void* const* d_in, const int* in_sizes, int n_in,
                              void* d_out, int out_size, void* d_ws, size_t ws_size,
                              hipStream_t stream) {
    const float* in = (const float*)d_in[0];
    const float* W1 = (const float*)d_in[1];
    const float* b1 = (const float*)d_in[2];
    const float* W2 = (const float*)d_in[3];
    const float* b2 = (const float*)d_in[4];
    const float* Wr = (const float*)d_in[5];
    const float* br = (const float*)d_in[6];
    const float* W3 = (const float*)d_in[7];
    const float* b3 = (const float*)d_in[8];
    const float* W4 = (const float*)d_in[9];
    const float* b4 = (const float*)d_in[10];
    const float* W5 = (const float*)d_in[11];
    const float* b5 = (const float*)d_in[12];
    float* out = (float*)d_out;

    const int BN = in_sizes[0] / IN;   // B*N = 12800
    locs_fused<<<BN / G, 128, 0, stream>>>(in, W1, b1, W2, b2, Wr, br,
                                           W3, b3, W4, b4, W5, b5, out);
}

// Round 6
// 170.215 us; speedup vs baseline: 6.0748x; 1.0347x over previous
//
#include <hip/hip_runtime.h>
#include <math.h>

#define EPSF 1e-7f
constexpr int NN  = 100;   // nodes per graph
constexpr int DEG = 99;    // fully-connected: deg = NN-1
constexpr int IN  = 6;
constexpr int H   = 128;
constexpr int G   = 4;     // nodes per block
constexpr float INV_PI = 0.3183098861837907f;

typedef __attribute__((ext_vector_type(8))) short short8;   // 8 bf16
typedef __attribute__((ext_vector_type(4))) float f32x4;

// d_ws layout in short8 units (total 12800 * 16B = 200 KB):
//   [0,512)      : W1 B-fragments, frag nt in 0..7, idx = nt*64 + L
//   [512,6656)   : W2/W3/W4 hi fragments, idx = 512 + ((layer*4+kt)*8+nt)*64 + L
//   [6656,12800) : lo fragments, same indexing + 6144
constexpr int WS_W1 = 0;
constexpr int WS_HI = 512;
constexpr int WS_LO = 6656;

__device__ __forceinline__ float clampf(float x, float lo, float hi) {
    return fminf(fmaxf(x, lo), hi);
}
__device__ __forceinline__ float fast_sig(float x) {
    return __builtin_amdgcn_rcpf(1.f + __expf(-x));
}
__device__ __forceinline__ unsigned short f2bf(float x) {   // RNE fp32->bf16
    unsigned int u = __float_as_uint(x);
    u = (u + 0x7FFFu + ((u >> 16) & 1u)) >> 16;
    return (unsigned short)u;
}
__device__ __forceinline__ float bf2f(unsigned short h) {
    return __uint_as_float(((unsigned int)h) << 16);
}
// fast atan2: octant-reduced minimax poly, ~1e-5 rad (features are bf16 anyway)
__device__ __forceinline__ float fast_atan2(float y, float x) {
    float ax = fabsf(x), ay = fabsf(y);
    float mx = fmaxf(ax, ay), mn = fminf(ax, ay);
    float r = mn * __builtin_amdgcn_rcpf(fmaxf(mx, 1e-35f));
    float r2 = r * r;
    float p = fmaf(r2, -0.01172120f, 0.05265332f);
    p = fmaf(r2, p, -0.11643287f);
    p = fmaf(r2, p, 0.19354346f);
    p = fmaf(r2, p, -0.33262347f);
    p = fmaf(r2, p, 0.99997726f);
    float t = r * p;
    t = (ay > ax) ? (1.5707963267948966f - t) : t;
    t = (x < 0.f) ? (3.14159265358979323f - t) : t;
    return copysignf(t, y);
}
__device__ __forceinline__ float fast_asin(float z) {       // |z| <= 1
    return fast_atan2(z, sqrtf(fmaxf(0.f, (1.f - z) * (1.f + z))));
}
__device__ __forceinline__ float fast_acos(float z) {       // |z| <= 1
    return fast_atan2(sqrtf(fmaxf(0.f, (1.f - z) * (1.f + z))), z);
}
__device__ __forceinline__ void vel_to_R(float vx, float vy, float vz, float* R) {
    float rho = sqrtf(vx * vx + vy * vy + vz * vz);
    float rxy = sqrtf(vx * vx + vy * vy);
    float inv = __builtin_amdgcn_rcpf(rxy);
    bool big = rxy > 1e-30f;
    float ct = big ? vx * inv : 1.f;
    float st = big ? vy * inv : 0.f;
    float cp = clampf(vz * __builtin_amdgcn_rcpf(rho + EPSF), -1.f, 1.f);
    float sp = sqrtf(fmaxf(0.f, 1.f - cp * cp));
    R[0] = cp * ct; R[1] = -st; R[2] = sp * ct;
    R[3] = cp * st; R[4] = ct;  R[5] = sp * st;
    R[6] = -sp;     R[7] = 0.f; R[8] = cp;
}

// ---------------- Kernel A: weights -> bf16 MFMA fragments in ws (rerun each
// launch; ws is re-poisoned). W2/W3/W4 stored as hi/lo bf16 split so the node
// MLP MFMA path is fp32-accurate (x*W = xh*Wh + xl*Wh + xh*Wl).
__global__ void conv_w(const float* __restrict__ W1, const float* __restrict__ W2,
                       const float* __restrict__ W3, const float* __restrict__ W4,
                       short8* __restrict__ ws) {
    int t = blockIdx.x * blockDim.x + threadIdx.x;
    if (t >= 104 * 64) return;
    int L = t & 63, f = t >> 6;
    int m = L & 15, qd = L >> 4;
    if (f < 8) {                          // W1 fragments (k<12 live, rest zero)
        int n = f * 16 + m;
        short8 v = 0;
#pragma unroll
        for (int j = 0; j < 8; ++j) {
            int k = qd * 8 + j;
            v[j] = (k < 12) ? (short)f2bf(W1[k * H + n]) : (short)0;
        }
        ws[WS_W1 + f * 64 + L] = v;
    } else {                              // node-MLP weight fragments, hi/lo
        int ff = f - 8;
        int layer = ff >> 5, rest = ff & 31;
        int kt = rest >> 3, nt = rest & 7;
        const float* W = (layer == 0) ? W2 : (layer == 1) ? W3 : W4;
        int n = nt * 16 + m;
        short8 hi = 0, lo = 0;
#pragma unroll
        for (int j = 0; j < 8; ++j) {
            float w = W[(kt * 32 + qd * 8 + j) * H + n];
            unsigned short h = f2bf(w);
            hi[j] = (short)h;
            lo[j] = (short)f2bf(w - bf2f(h));
        }
        int idx = ((layer * 4 + kt) * 8 + nt) * 64 + L;
        ws[WS_HI + idx] = hi;
        ws[WS_LO + idx] = lo;
    }
}

// ---------------- Kernel B: fully fused LoCS layer. One block = 4 nodes.
__global__ __launch_bounds__(128)
void locs_fused(const float* __restrict__ in,
                const float* __restrict__ W1, const float* __restrict__ b1,
                const float* __restrict__ b2,
                const float* __restrict__ Wr, const float* __restrict__ br,
                const float* __restrict__ b3, const float* __restrict__ b4,
                const float* __restrict__ W5, const float* __restrict__ b5,
                const short8* __restrict__ wfrag,
                float* __restrict__ out) {
    __shared__ short8 eaA[7 * 64];     // A fragments: 7 edge-tiles x 64 lanes
    __shared__ float baseF[G][H];      // folded silu bias per (node, channel)
    __shared__ float xF[G][H];         // hsum / activations (fp32)
    __shared__ float rmF[G][16];       // R(9) + cv(3) + pos(3) per node
    __shared__ float pbF[G][96];       // W5 partial sums
    __shared__ float predF[G][8];

    const int tid = threadIdx.x;
    const int L   = tid & 63;
    const int wv  = tid >> 6;
    const int q   = L >> 4;
    const int lm  = L & 15;
    const int bn0 = blockIdx.x * G;

    // ---- setup: zero A-fragment buffer (pad rows/k stay zero)
    {
        short8 z = 0;
#pragma unroll
        for (int i = 0; i < 4; ++i) {
            int idx = tid + i * 128;
            if (idx < 7 * 64) eaA[idx] = z;
        }
    }
    // ---- setup: R + canon_vel + pos for the 4 nodes
    if (tid < G) {
        const float* xi = in + (bn0 + tid) * IN;
        float R[9];
        vel_to_R(xi[3], xi[4], xi[5], R);
#pragma unroll
        for (int k = 0; k < 9; ++k) rmF[tid][k] = R[k];
        rmF[tid][9]  = R[0] * xi[3] + R[3] * xi[4] + R[6] * xi[5];
        rmF[tid][10] = R[1] * xi[3] + R[4] * xi[4] + R[7] * xi[5];
        rmF[tid][11] = R[2] * xi[3] + R[5] * xi[4] + R[8] * xi[5];
        rmF[tid][12] = xi[0]; rmF[tid][13] = xi[1]; rmF[tid][14] = xi[2];
    }
    __syncthreads();

    // folded silu bias: b1 + cv_g . W1[15..17]
    {
        float w15 = W1[15 * H + tid], w16 = W1[16 * H + tid], w17 = W1[17 * H + tid];
        float b1c = b1[tid];
#pragma unroll
        for (int g = 0; g < G; ++g)
            baseF[g][tid] = b1c + rmF[g][9] * w15 + rmF[g][10] * w16 + rmF[g][11] * w17;
    }
    // W1 B-fragments from ws (this wave's 4 channel-tiles)
    short8 bfr[4];
#pragma unroll
    for (int i = 0; i < 4; ++i) bfr[i] = wfrag[WS_W1 + (wv * 4 + i) * 64 + L];

    const int bB = bn0 / NN;           // all 4 nodes in same graph (100 % 4 == 0)
    const int n0 = bn0 - bB * NN;

    // ---- per-node edge phase
    for (int g = 0; g < G; ++g) {
        __syncthreads();   // prior MFMA reads of eaA complete
        int nG = n0 + g;
        if (tid < DEG) {
            int s = tid < nG ? tid : tid + 1;          // implicit ~eye edge list
            float Rn[9];
#pragma unroll
            for (int k = 0; k < 9; ++k) Rn[k] = rmF[g][k];
            float pix = rmF[g][12], piy = rmF[g][13], piz = rmF[g][14];
            const float* xj = in + (bB * NN + s) * IN;
            float rel0 = xj[0] - pix, rel1 = xj[1] - piy, rel2 = xj[2] - piz;
            float vjx = xj[3], vjy = xj[4], vjz = xj[5];
            float Rs[9];
            vel_to_R(vjx, vjy, vjz, Rs);
            float rr0 = Rn[0] * rel0 + Rn[3] * rel1 + Rn[6] * rel2;
            float rr1 = Rn[1] * rel0 + Rn[4] * rel1 + Rn[7] * rel2;
            float rr2 = Rn[2] * rel0 + Rn[5] * rel1 + Rn[8] * rel2;
            float ro00 = Rn[0] * Rs[0] + Rn[3] * Rs[3] + Rn[6] * Rs[6];
            float ro10 = Rn[1] * Rs[0] + Rn[4] * Rs[3] + Rn[7] * Rs[6];
            float ro20 = Rn[2] * Rs[0] + Rn[5] * Rs[3] + Rn[8] * Rs[6];
            float ro21 = Rn[2] * Rs[1] + Rn[5] * Rs[4] + Rn[8] * Rs[7];
            float ro22 = Rn[2] * Rs[2] + Rn[5] * Rs[5] + Rn[8] * Rs[8];
            float d[12];
            d[0] = rr0; d[1] = rr1; d[2] = rr2;
            d[3] = fast_atan2(ro10, ro00) * INV_PI;
            d[4] = fast_asin(clampf(-ro20, -1.f, 1.f)) * INV_PI;
            d[5] = fast_atan2(ro21, ro22) * INV_PI;
            float dist = sqrtf(rel0 * rel0 + rel1 * rel1 + rel2 * rel2);
            d[6] = dist;                                   // |rot_rel| == |rel|
            d[7] = fast_atan2(rr1, rr0);
            d[8] = fast_acos(clampf(rr2 * __builtin_amdgcn_rcpf(dist + EPSF), -1.f, 1.f));
            d[9]  = Rn[0] * vjx + Rn[3] * vjy + Rn[6] * vjz;
            d[10] = Rn[1] * vjx + Rn[4] * vjy + Rn[7] * vjz;
            d[11] = Rn[2] * vjx + Rn[5] * vjy + Rn[8] * vjz;
            short8 lo = 0, hi = 0;
#pragma unroll
            for (int k = 0; k < 8; ++k) lo[k] = (short)f2bf(d[k]);
#pragma unroll
            for (int k = 0; k < 4; ++k) hi[k] = (short)f2bf(d[8 + k]);
            int t = tid >> 4, m = tid & 15;
            eaA[t * 64 +      m] = lo;
            eaA[t * 64 + 16 + m] = hi;
        }
        __syncthreads();

        // MFMA (bias in C-operand) + silu + row-accumulate
        float part[4] = {0.f, 0.f, 0.f, 0.f};
        f32x4 c0, c1, c2, c3;
        {
            float bs0 = baseF[g][wv * 64 +  0 + lm];
            float bs1 = baseF[g][wv * 64 + 16 + lm];
            float bs2 = baseF[g][wv * 64 + 32 + lm];
            float bs3 = baseF[g][wv * 64 + 48 + lm];
            c0 = (f32x4){bs0, bs0, bs0, bs0};
            c1 = (f32x4){bs1, bs1, bs1, bs1};
            c2 = (f32x4){bs2, bs2, bs2, bs2};
            c3 = (f32x4){bs3, bs3, bs3, bs3};
        }
#pragma unroll
        for (int t = 0; t < 6; ++t) {
            short8 a = eaA[t * 64 + L];
            f32x4 d0 = __builtin_amdgcn_mfma_f32_16x16x32_bf16(a, bfr[0], c0, 0, 0, 0);
            f32x4 d1 = __builtin_amdgcn_mfma_f32_16x16x32_bf16(a, bfr[1], c1, 0, 0, 0);
            f32x4 d2 = __builtin_amdgcn_mfma_f32_16x16x32_bf16(a, bfr[2], c2, 0, 0, 0);
            f32x4 d3 = __builtin_amdgcn_mfma_f32_16x16x32_bf16(a, bfr[3], c3, 0, 0, 0);
#pragma unroll
            for (int r = 0; r < 4; ++r) {
                part[0] += d0[r] * fast_sig(d0[r]);
                part[1] += d1[r] * fast_sig(d1[r]);
                part[2] += d2[r] * fast_sig(d2[r]);
                part[3] += d3[r] * fast_sig(d3[r]);
            }
        }
        {   // tail tile: edges 96..98 (q==0, r<3)
            short8 a = eaA[6 * 64 + L];
            f32x4 d0 = __builtin_amdgcn_mfma_f32_16x16x32_bf16(a, bfr[0], c0, 0, 0, 0);
            f32x4 d1 = __builtin_amdgcn_mfma_f32_16x16x32_bf16(a, bfr[1], c1, 0, 0, 0);
            f32x4 d2 = __builtin_amdgcn_mfma_f32_16x16x32_bf16(a, bfr[2], c2, 0, 0, 0);
            f32x4 d3 = __builtin_amdgcn_mfma_f32_16x16x32_bf16(a, bfr[3], c3, 0, 0, 0);
            bool ok = (q == 0);
#pragma unroll
            for (int r = 0; r < 3; ++r) {
                part[0] += ok ? d0[r] * fast_sig(d0[r]) : 0.f;
                part[1] += ok ? d1[r] * fast_sig(d1[r]) : 0.f;
                part[2] += ok ? d2[r] * fast_sig(d2[r]) : 0.f;
                part[3] += ok ? d3[r] * fast_sig(d3[r]) : 0.f;
            }
        }
#pragma unroll
        for (int i = 0; i < 4; ++i) {
            float v = part[i];
            v += __shfl_xor(v, 16, 64);
            v += __shfl_xor(v, 32, 64);
            if (L < 16) xF[g][wv * 64 + i * 16 + L] = v;
        }
    }

    // ---- node MLP: 3 layers via hi/lo bf16 MFMA (fp32-accurate)
#pragma unroll
    for (int layer = 0; layer < 3; ++layer) {
        __syncthreads();               // xF (input activations) ready
        // A fragments: lane row = lm (rows 0..3 live = the 4 nodes)
        bool rv = (lm < 4);
        short8 ah[4], al[4];
#pragma unroll
        for (int kt = 0; kt < 4; ++kt) {
            short8 h = 0, lo = 0;
            if (rv) {
                const f32x4* xp = (const f32x4*)&xF[lm][kt * 32 + q * 8];
                f32x4 x0 = xp[0], x1 = xp[1];
                float xv[8] = {x0.x, x0.y, x0.z, x0.w, x1.x, x1.y, x1.z, x1.w};
#pragma unroll
                for (int j = 0; j < 8; ++j) {
                    unsigned short hh = f2bf(xv[j]);
                    h[j] = (short)hh;
                    lo[j] = (short)f2bf(xv[j] - bf2f(hh));
                }
            }
            ah[kt] = h; al[kt] = lo;
        }
        f32x4 acc[4];
#pragma unroll
        for (int i = 0; i < 4; ++i) acc[i] = (f32x4){0.f, 0.f, 0.f, 0.f};
#pragma unroll
        for (int kt = 0; kt < 4; ++kt) {
            int base = ((layer * 4 + kt) * 8 + wv * 4) * 64 + L;
#pragma unroll
            for (int i = 0; i < 4; ++i) {
                short8 bh = wfrag[WS_HI + base + i * 64];
                short8 bl = wfrag[WS_LO + base + i * 64];
                acc[i] = __builtin_amdgcn_mfma_f32_16x16x32_bf16(ah[kt], bh, acc[i], 0, 0, 0);
                acc[i] = __builtin_amdgcn_mfma_f32_16x16x32_bf16(al[kt], bh, acc[i], 0, 0, 0);
                acc[i] = __builtin_amdgcn_mfma_f32_16x16x32_bf16(ah[kt], bl, acc[i], 0, 0, 0);
            }
        }
        __syncthreads();               // all xF reads done before overwrite
        if (L < 16) {                  // quad 0 holds rows 0..3 (the 4 nodes)
#pragma unroll
            for (int i = 0; i < 4; ++i) {
                int ch = wv * 64 + i * 16 + lm;
                if (layer == 0) {
                    float b2c = b2[ch], brc = br[ch];
                    float w3c = Wr[3 * H + ch], w4c = Wr[4 * H + ch], w5c = Wr[5 * H + ch];
#pragma unroll
                    for (int r = 0; r < 4; ++r)
                        xF[r][ch] = acc[i][r] * (1.f / 99.f) + b2c
                                  + rmF[r][9] * w3c + rmF[r][10] * w4c
                                  + rmF[r][11] * w5c + brc;
                } else {
                    float bb = (layer == 1) ? b3[ch] : b4[ch];
#pragma unroll
                    for (int r = 0; r < 4; ++r)
                        xF[r][ch] = fmaxf(0.f, acc[i][r] + bb);
                }
            }
        }
    }
    __syncthreads();

    // ---- pred = p2 @ W5 + b5, then rotate + residual
    if (tid < 96) {
        int o = tid >> 4, sl = tid & 15, kb = sl * 8;
        float w5[8];
#pragma unroll
        for (int j = 0; j < 8; ++j) w5[j] = W5[(kb + j) * IN + o];
#pragma unroll
        for (int g = 0; g < G; ++g) {
            float s = 0.f;
#pragma unroll
            for (int j = 0; j < 8; ++j) s = fmaf(xF[g][kb + j], w5[j], s);
            pbF[g][sl * 6 + o] = s;
        }
    }
    __syncthreads();
    if (tid < 24) {
        int g = tid / 6, o = tid - g * 6;
        float s = b5[o];
#pragma unroll
        for (int sl = 0; sl < 16; ++sl) s += pbF[g][sl * 6 + o];
        predF[g][o] = s;
    }
    __syncthreads();
    if (tid < 24) {
        int g = tid / 6, o = tid - g * 6;
        int r = (o < 3) ? o : o - 3;
        int off = (o < 3) ? 0 : 3;
        float gl = rmF[g][r * 3 + 0] * predF[g][off + 0]
                 + rmF[g][r * 3 + 1] * predF[g][off + 1]
                 + rmF[g][r * 3 + 2] * predF[g][off + 2];
        int bng = bn0 + g;
        out[bng * IN + o] = in[bng * IN + o] + gl;
    }
}

extern "C" void kernel_launch(void* const* d_in, const int* in_sizes, int n_in,
                              void* d_out, int out_size, void* d_ws, size_t ws_size,
                              hipStream_t stream) {
    const float* in = (const float*)d_in[0];
    const float* W1 = (const float*)d_in[1];
    const float* b1 = (const float*)d_in[2];
    const float* W2 = (const float*)d_in[3];
    const float* b2 = (const float*)d_in[4];
    const float* Wr = (const float*)d_in[5];
    const float* br = (const float*)d_in[6];
    const float* W3 = (const float*)d_in[7];
    const float* b3 = (const float*)d_in[8];
    const float* W4 = (const float*)d_in[9];
    const float* b4 = (const float*)d_in[10];
    const float* W5 = (const float*)d_in[11];
    const float* b5 = (const float*)d_in[12];
    float* out = (float*)d_out;

    short8* wsF = (short8*)d_ws;       // 200 KB of fragments

    const int BN = in_sizes[0] / IN;   // B*N = 12800
    conv_w<<<26, 256, 0, stream>>>(W1, W2, W3, W4, wsF);
    locs_fused<<<BN / G, 128, 0, stream>>>(in, W1, b1, b2, Wr, br, b3, b4,
                                           W5, b5, wsF, out);
}